// Round 8
// baseline (182.493 us; speedup 1.0000x reference)
//
#include <hip/hip_runtime.h>

// LSTM: T=512, B=4096, IN=1, H=12.
// R18 = R11 (proven 130.4us: DPP ror-gather, NO LDS on recurrence chain,
// delayed ring-fc filler) + amdgpu_waves_per_eu(1,1) + rcp-pairing.
//
// Why (R17 post-mortem): residency fix on R12 was a wash - VGPR 56->132
// but dur 122.5->123.6, because R12's weight reloads hid under its LDS
// h-round-trip stalls (VALUBusy 51%). Decomposition of R12's wall:
// RT_LDS(~200) + issue(~290) + tail(~80) = 574: ALL per-step work
// (matvec AND fc filler) depends on the h read -> RT serializes. R11's
// structure has NO RT (DPP hops ~4cyc) and was ISSUE-bound at 380cyc
// (62% x 611); op-count at trans=16cyc is ~300 -> the ~80 excess is
// weight-reload issue, NOT hidden there. So apply the residency fix
// where it isn't masked:
//  - amdgpu_waves_per_eu(1,1): kernel genuinely runs 1 wave/SIMD (1024
//    single-wave blocks on 1024 SIMDs); license the full VGPR file so
//    the per-source weight tables stay resident. Tell: VGPR ~110-140.
//  - rcp-pairing (numerics proven R16/R17, absmax 9.77e-4): si,sf from
//    ONE rcp((1+Ei)(1+Ef)); rg,so from ONE rcp((1+Eg)(1+Eo)). -2 trans
//    (= -32 cyc issue at 16 cyc/trans), +6 muls (+12). |h|<=1 always
//    (hn = so*(1-2rc)) -> gates small -> products finite.
// Predicted issue ~280, wall ~450-510 cyc/step -> 95-108us.
//
// R11 structure (unchanged, proven):
//  - one cell per 16-lane DPP row (j=lane&15; lanes 12..15 finite
//    clones), 4 cells/wave, 1024 single-wave blocks.
//  - h exchanged with 15 v_mov_b32 dpp row_ror (direction probed at
//    setup; per-source-slot weight tables, zero-gated clone sources).
//  - gates: 2-way-split pk_fma chains, weights pre-scaled (sigmoid:
//    -log2e, tanh-g: +2log2e) -> activations rcp(1+exp2(g)).
//  - x-proj + bias folded into chain HEAD; xq prefetched one 4-step
//    group ahead; X chunk-staged to LDS transposed/padded (XPAD=68).
//  - cell state pre-scaled: c2 = 2log2e*c.
//  - fc: ring ror-reduce DELAYED one step, halves placed in the two
//    exp2->rcp stall windows; fake t=0 store aliases out[0] then
//    overwritten; epilogue flushes t=511.

#define TT    512
#define NB    4096
#define HH    12
#define RPW   4      // rows (cells) per wave
#define CHUNK 64     // X staging chunk; TT % CHUNK == 0
#define XPAD  68     // padded row stride (floats): +4 breaks bank aliasing

typedef float v2f __attribute__((ext_vector_type(2)));

static __device__ __forceinline__ v2f pkfma(v2f a, v2f b, v2f c) {
#if __has_builtin(__builtin_elementwise_fma)
    return __builtin_elementwise_fma(a, b, c);
#else
    v2f r; r.x = fmaf(a.x, b.x, c.x); r.y = fmaf(a.y, b.y, c.y); return r;
#endif
}

#define SNEG   (-1.44269504088896340736f)   // sigmoid pre-scale: -log2(e)
#define SPOS   ( 2.88539008177792681472f)   // tanh pre-scale: +2*log2(e)
#define M2SPOS (-5.77078016355585362944f)   // -2*SPOS

#define ROR(r) (0x120 + (r))                // DPP ctrl: row_ror:r

__global__ __launch_bounds__(64)
__attribute__((amdgpu_waves_per_eu(1, 1)))
void lstm_fused(const float* __restrict__ X,
                const float* __restrict__ W_ih,
                const float* __restrict__ W_hh,
                const float* __restrict__ b_ih,
                const float* __restrict__ b_hh,
                const float* __restrict__ fc_w,
                const float* __restrict__ fc_b,
                float* __restrict__ out)
{
    __shared__ float xchunk[RPW][XPAD];   // transposed + padded: [row][time]

    const int lane = threadIdx.x;        // 0..63
    const int row  = lane >> 4;          // 0..3  : cell slot
    const int j    = lane & 15;          // 0..11 real, 12..15 clone lanes
    const int cellbase = blockIdx.x * RPW;
    const int cell = cellbase + row;     // grid sized so cell < NB always

    // ---- probe DPP ror direction: sid[r] = within-row source lane of ror r
    int sid[16];
    sid[0] = j;
#define PROBE(r) sid[r] = __builtin_amdgcn_update_dpp(0, j, ROR(r), 0xF, 0xF, true);
    PROBE(1)  PROBE(2)  PROBE(3)  PROBE(4)  PROBE(5)
    PROBE(6)  PROBE(7)  PROBE(8)  PROBE(9)  PROBE(10)
    PROBE(11) PROBE(12) PROBE(13) PROBE(14) PROBE(15)
#undef PROBE

    // ---- per-source-slot gate weight tables (r=0 is local contribution)
    const int jc = (j < HH) ? j : (HH - 1);   // clamp clone lanes (finite)
    v2f wifU[16], wgoU[16];
    #pragma unroll
    for (int r = 0; r < 16; ++r) {
        const int  s  = sid[r];
        const int  sc = (s < HH) ? s : (HH - 1);
        const float g = ((j >= HH) || (s < HH)) ? 1.0f : 0.0f;
        wifU[r].x = g * SNEG * W_hh[(0 * HH + jc) * HH + sc];
        wifU[r].y = g * SNEG * W_hh[(1 * HH + jc) * HH + sc];
        wgoU[r].x = g * SPOS * W_hh[(2 * HH + jc) * HH + sc];
        wgoU[r].y = g * SNEG * W_hh[(3 * HH + jc) * HH + sc];
    }
    v2f bif, bgo, wxif, wxgo;
    bif.x  = SNEG * (b_ih[0 * HH + jc] + b_hh[0 * HH + jc]);
    bif.y  = SNEG * (b_ih[1 * HH + jc] + b_hh[1 * HH + jc]);
    bgo.x  = SPOS * (b_ih[2 * HH + jc] + b_hh[2 * HH + jc]);
    bgo.y  = SNEG * (b_ih[3 * HH + jc] + b_hh[3 * HH + jc]);
    wxif.x = SNEG * W_ih[0 * HH + jc];   // IN == 1, W_ih flat [48]
    wxif.y = SNEG * W_ih[1 * HH + jc];
    wxgo.x = SPOS * W_ih[2 * HH + jc];
    wxgo.y = SNEG * W_ih[3 * HH + jc];
    const float fcb  = fc_b[0];
    const float fcwj = (j < HH) ? fc_w[j] : 0.0f;   // clones contribute 0

    float c2 = 0.0f;    // pre-scaled cell state: SPOS * c[cell][j]
    float hn = 0.0f;    // my h element h[cell][j]  (h0 = 0)
    int hbits = 0;

    // delayed-output state: pPend = prev step's hn*fcw partial,
    // offPrev = byte offset of prev step's row. Fake t=0 store aliases
    // out[0][cell]; real t=0 store overwrites it one step later.
    float pPend = 0.0f;
    unsigned offPrev = 0;
    float* const outp = out + cell;

    // prefetch chunk 0 of X into registers
    float4 gq = *(const float4*)(X + (size_t)lane * NB + cellbase);

    for (int tc = 0; tc < TT; tc += CHUNK) {
        // stage prefetched chunk to LDS (transposed/padded), prefetch next
        xchunk[0][lane] = gq.x;
        xchunk[1][lane] = gq.y;
        xchunk[2][lane] = gq.z;
        xchunk[3][lane] = gq.w;
        if (tc + CHUNK < TT)
            gq = *(const float4*)(X + (size_t)(tc + CHUNK + lane) * NB + cellbase);

        // x for the first 4-step group of this chunk
        float4 xq_next = *(const float4*)&xchunk[row][0];

        for (int t4 = 0; t4 < CHUNK; t4 += 4) {
            const float4 xq = xq_next;                       // group t4
            const int nx = (t4 + 4 < CHUNK) ? (t4 + 4) : t4; // clamp tail
            xq_next = *(const float4*)&xchunk[row][nx];      // prefetch next
            const float xs[4] = {xq.x, xq.y, xq.z, xq.w};

            #pragma unroll
            for (int u = 0; u < 4; ++u) {
                // chain HEAD: bias + x-projection (operands ready a group
                // early; off the h-critical path)
                v2f xvv; xvv.x = xs[u]; xvv.y = xs[u];
                v2f gifA = pkfma(xvv, wxif, bif);
                v2f goA  = pkfma(xvv, wxgo, bgo);
                v2f gifB; gifB.x = 0.0f; gifB.y = 0.0f;
                v2f goB;  goB.x  = 0.0f; goB.y  = 0.0f;
                {   // local contribution (r = 0)
                    v2f hk; hk.x = hn; hk.y = hn;
                    gifA = pkfma(wifU[0], hk, gifA);
                    goA  = pkfma(wgoU[0], hk, goA);
                }
#define XR(r) { \
                const int hr_##r = __builtin_amdgcn_update_dpp(0, hbits, ROR(r), 0xF, 0xF, true); \
                const float hf = __int_as_float(hr_##r); \
                v2f hk; hk.x = hf; hk.y = hf; \
                if ((r) < 8) { gifA = pkfma(wifU[r], hk, gifA); goA = pkfma(wgoU[r], hk, goA); } \
                else         { gifB = pkfma(wifU[r], hk, gifB); goB = pkfma(wgoU[r], hk, goB); } }
                XR(1)  XR(2)  XR(3)  XR(4)  XR(5)
                XR(6)  XR(7)  XR(8)  XR(9)  XR(10)
                XR(11) XR(12) XR(13) XR(14) XR(15)
#undef XR
                const v2f gif = gifA + gifB;     // v_pk_add_f32
                const v2f ggo = goA + goB;

                // gate exponentials
                const float Ei = __builtin_amdgcn_exp2f(gif.x);
                const float Ef = __builtin_amdgcn_exp2f(gif.y);
                const float Eg = __builtin_amdgcn_exp2f(ggo.x);
                const float Eo = __builtin_amdgcn_exp2f(ggo.y);

                // delayed fc-reduce (PREVIOUS step), first half: fills the
                // gate exp2->rcp window (incl. its own DPP RAW bubbles)
                float p = pPend;
                p += __int_as_float(__builtin_amdgcn_update_dpp(0, __float_as_int(p), ROR(8), 0xF, 0xF, true));
                p += __int_as_float(__builtin_amdgcn_update_dpp(0, __float_as_int(p), ROR(4), 0xF, 0xF, true));

                // rcp-paired activations: one rcp per gate pair
                const float dI = 1.0f + Ei;
                const float dF = 1.0f + Ef;
                const float dG = 1.0f + Eg;
                const float dO = 1.0f + Eo;
                const float rif = __builtin_amdgcn_rcpf(dI * dF);
                const float rgo = __builtin_amdgcn_rcpf(dG * dO);
                const float si = dF * rif;     // 1/(1+Ei)
                const float sf = dI * rif;     // 1/(1+Ef)
                const float rg = dO * rgo;     // 1/(1+Eg)
                const float so = dG * rgo;     // 1/(1+Eo)

                // pre-scaled cell update: c2 = sf*c2 + si*(SPOS*tanh-arg)
                const float tgS = fmaf(M2SPOS, rg, SPOS);
                c2 = fmaf(sf, c2, si * tgS);
                const float Ec = __builtin_amdgcn_exp2f(c2);   // exp2(SPOS*c)

                // delayed fc-reduce, second half + store: fills the
                // tanh(c) exp2->rcp window
                p += __int_as_float(__builtin_amdgcn_update_dpp(0, __float_as_int(p), ROR(2), 0xF, 0xF, true));
                p += __int_as_float(__builtin_amdgcn_update_dpp(0, __float_as_int(p), ROR(1), 0xF, 0xF, true));
                if (j == 0) *(float*)((char*)outp + offPrev) = p + fcb;

                const float rc   = __builtin_amdgcn_rcpf(1.0f + Ec);
                const float m2so = -2.0f * so;
                hn    = fmaf(m2so, rc, so);
                hbits = __float_as_int(hn);

                // stage this step's output partial for next step's windows
                pPend   = hn * fcwj;
                offPrev = (unsigned)(tc + t4 + u) << 14;   // t * NB * 4B
            }
        }
    }

    // epilogue: flush the final pending output (t = 511)
    {
        float p = pPend;
        p += __int_as_float(__builtin_amdgcn_update_dpp(0, __float_as_int(p), ROR(8), 0xF, 0xF, true));
        p += __int_as_float(__builtin_amdgcn_update_dpp(0, __float_as_int(p), ROR(4), 0xF, 0xF, true));
        p += __int_as_float(__builtin_amdgcn_update_dpp(0, __float_as_int(p), ROR(2), 0xF, 0xF, true));
        p += __int_as_float(__builtin_amdgcn_update_dpp(0, __float_as_int(p), ROR(1), 0xF, 0xF, true));
        if (j == 0) *(float*)((char*)outp + offPrev) = p + fcb;
    }
}

extern "C" void kernel_launch(void* const* d_in, const int* in_sizes, int n_in,
                              void* d_out, int out_size, void* d_ws, size_t ws_size,
                              hipStream_t stream) {
    const float* X    = (const float*)d_in[0];
    const float* W_ih = (const float*)d_in[1];
    const float* W_hh = (const float*)d_in[2];
    const float* b_ih = (const float*)d_in[3];
    const float* b_hh = (const float*)d_in[4];
    const float* fc_w = (const float*)d_in[5];
    const float* fc_b = (const float*)d_in[6];
    float* out = (float*)d_out;

    const int grid = NB / RPW;   // 1024 single-wave blocks: every SIMD busy
    lstm_fused<<<grid, 64, 0, stream>>>(X, W_ih, W_hh, b_ih, b_hh, fc_w, fc_b, out);
}